// Round 4
// baseline (292.095 us; speedup 1.0000x reference)
//
#include <hip/hip_runtime.h>
#include <hip/hip_bf16.h>
#include <math.h>

#define B_ 64
#define L_ 512
#define D_ 768
#define H_ 384
#define T_ 9
#define M_ (B_ * L_)   // 32768 rows

typedef __attribute__((ext_vector_type(8))) short short8;
typedef __attribute__((ext_vector_type(4))) float f32x4;

__device__ __forceinline__ unsigned short f2bf(float f) {
    unsigned u = __float_as_uint(f);
    u += 0x7FFFu + ((u >> 16) & 1u);   // RNE
    return (unsigned short)(u >> 16);
}

// packed f32x2 -> bf16x2 (v_cvt_pk_bf16_f32 on gfx950)
__device__ __forceinline__ unsigned pkbf2(float a, float b) {
    __hip_bfloat162 h = __float22bfloat162_rn(float2{a, b});
    return *(unsigned*)&h;
}

// tanh-form gelu as x * sigmoid(2*0.79788456*(x + 0.044715 x^3)) — 1 exp.
__device__ __forceinline__ float gelu_fast(float x) {
    float z2 = 1.5957691216f * x + 0.0713548162726f * x * x * x;
    return x / (1.f + __expf(-z2));
}

__device__ __forceinline__ float wredf(float v) {
#pragma unroll
    for (int m = 32; m >= 1; m >>= 1) v += __shfl_xor(v, m, 64);
    return v;
}

// pack 8 f32 -> bf16x8 fragment
__device__ __forceinline__ short8 pack8(f32x4 a, f32x4 b) {
    int4 v = {(int)pkbf2(a[0], a[1]), (int)pkbf2(a[2], a[3]),
              (int)pkbf2(b[0], b[1]), (int)pkbf2(b[2], b[3])};
    return *(short8*)&v;
}

// -----------------------------------------------------------------------------
// Kernel 0: fragment-ordered bf16 weights + zero d_out.
//   W1F[((nt*24 + kc)*64 + lane)*8 + j] = W1[kc*32 + q*8 + j][nt*16 + lm]
//   W2F[(kk*64 + lane)*8 + j]           = (lm<9) ? W2[kk*32 + q*8 + j][lm] : 0
// -----------------------------------------------------------------------------
__global__ __launch_bounds__(256) void prep_kernel(
    const float* __restrict__ W1, const float* __restrict__ W2,
    unsigned short* __restrict__ W1F, unsigned short* __restrict__ W2F,
    float* __restrict__ out)
{
    if (blockIdx.x == 0 && threadIdx.x == 0) out[0] = 0.f;
    const int g    = blockIdx.x * 4 + (threadIdx.x >> 6);
    const int lane = threadIdx.x & 63;
    const int lm   = lane & 15;
    const int q    = lane >> 4;
    if (g < 576) {                       // W1F: g = nt*24 + kc
        const int nt = g / 24;
        const int kc = g - nt * 24;
        const int n  = nt * 16 + lm;
        short8 v;
#pragma unroll
        for (int j = 0; j < 8; ++j)
            v[j] = (short)f2bf(W1[(size_t)(kc * 32 + q * 8 + j) * H_ + n]);
        *(short8*)(W1F + ((size_t)g * 64 + lane) * 8) = v;
    } else if (g < 588) {                // W2F: kk = g - 576
        const int kk = g - 576;
        short8 v;
#pragma unroll
        for (int j = 0; j < 8; ++j) {
            int k = kk * 32 + q * 8 + j;
            v[j] = (lm < 9) ? (short)f2bf(W2[(size_t)k * T_ + lm]) : (short)0;
        }
        *(short8*)(W2F + ((size_t)kk * 64 + lane) * 8) = v;
    }
}

// -----------------------------------------------------------------------------
// Kernel 1: partial emissions. Grid 1024 = 512 row-blocks x 2 n-halves
// (blockIdx = rb + 512*half; 512%8==0 so twins share an XCD for X L2 reuse).
// BM=64, BN=192, 256 thr, 4 waves (each: 4 m-tiles x 3 n-tiles = 12 MFMA/iter).
//
// NO LDS / NO BARRIERS in the main loop (round-3 lesson): A-tile (192 KB/blk)
// and W1F (576 KB) are L2/L3-resident, so each lane loads its MFMA A-fragment
// DIRECTLY from global (2x f32x4 = 32 B, 128B-segment coalesced per row),
// converts with v_cvt_pk_bf16_f32, and feeds MFMA. The 24 k-steps are fully
// unrolled; with no barrier in the way the compiler software-pipelines the
// ~11 independent loads/iter across iterations. Latency hiding = ILP x TLP
// (12 waves/CU at launch_bounds(256,3)). This deletes the LDS round-trip
// (320 cy/blk-step of LDS pipe), the 4x redundant fp32->bf16 conversion, the
// bank conflicts (row stride was 128 B = 32 banks: swizzle could never work),
// and the vmcnt/barrier lockstep that kept every pipe <30% busy.
// Epilogue: gelu -> Hs (25.6 KB LDS, one-shot) -> 6 MFMA vs W2F half -> em.
// -----------------------------------------------------------------------------
__global__ __launch_bounds__(256, 3) void emis_mfma_kernel(
    const float* __restrict__ X,             // [M_][768] fp32
    const unsigned short* __restrict__ W1F,
    const float* __restrict__ b1,
    const unsigned short* __restrict__ W2F,
    const float* __restrict__ b2,
    float* __restrict__ em0,                 // [M_][9] half-0 partials (+b2)
    float* __restrict__ em1)                 // [M_][9] half-1 partials
{
    __shared__ __align__(16) unsigned short Hs[64 * 200];  // 25.6 KB

    const int t    = threadIdx.x;
    const int lane = t & 63;
    const int w    = t >> 6;
    const int lm   = lane & 15;
    const int q    = lane >> 4;
    const int half = blockIdx.x >> 9;
    const int rb   = blockIdx.x & 511;
    const int row0 = rb * 64;

    const int ntg0 = half * 12 + w * 3;      // first global n-tile of this wave

    // per-lane A-row pointers: lane (lm,q) of m-tile mt reads
    // X[row0 + mt*16 + lm][kc*32 + q*8 .. +8]  (fragment k = q*8+j)
    const float* xr0 = X + (size_t)(row0 +  0 + lm) * D_ + (q << 3);
    const float* xr1 = xr0 + (size_t)16 * D_;
    const float* xr2 = xr0 + (size_t)32 * D_;
    const float* xr3 = xr0 + (size_t)48 * D_;

    const unsigned short* wp0 = W1F + ((size_t)(ntg0 + 0) * 24 * 64 + lane) * 8;
    const unsigned short* wp1 = W1F + ((size_t)(ntg0 + 1) * 24 * 64 + lane) * 8;
    const unsigned short* wp2 = W1F + ((size_t)(ntg0 + 2) * 24 * 64 + lane) * 8;

    f32x4 acc[4][3];
#pragma unroll
    for (int mt = 0; mt < 4; ++mt)
#pragma unroll
        for (int i = 0; i < 3; ++i) acc[mt][i] = (f32x4)0.f;

#pragma unroll
    for (int kc = 0; kc < 24; ++kc) {
        // A fragments straight from global (L1/L2-hot), cvt_pk to bf16x8
        short8 af0 = pack8(*(const f32x4*)(xr0 + kc * 32),
                           *(const f32x4*)(xr0 + kc * 32 + 4));
        short8 af1 = pack8(*(const f32x4*)(xr1 + kc * 32),
                           *(const f32x4*)(xr1 + kc * 32 + 4));
        short8 af2 = pack8(*(const f32x4*)(xr2 + kc * 32),
                           *(const f32x4*)(xr2 + kc * 32 + 4));
        short8 af3 = pack8(*(const f32x4*)(xr3 + kc * 32),
                           *(const f32x4*)(xr3 + kc * 32 + 4));
        // B fragments (W1F is fragment-ordered: stride 512 shorts per kc)
        short8 bw0 = *(const short8*)(wp0 + (size_t)kc * 512);
        short8 bw1 = *(const short8*)(wp1 + (size_t)kc * 512);
        short8 bw2 = *(const short8*)(wp2 + (size_t)kc * 512);

        acc[0][0] = __builtin_amdgcn_mfma_f32_16x16x32_bf16(af0, bw0, acc[0][0], 0, 0, 0);
        acc[0][1] = __builtin_amdgcn_mfma_f32_16x16x32_bf16(af0, bw1, acc[0][1], 0, 0, 0);
        acc[0][2] = __builtin_amdgcn_mfma_f32_16x16x32_bf16(af0, bw2, acc[0][2], 0, 0, 0);
        acc[1][0] = __builtin_amdgcn_mfma_f32_16x16x32_bf16(af1, bw0, acc[1][0], 0, 0, 0);
        acc[1][1] = __builtin_amdgcn_mfma_f32_16x16x32_bf16(af1, bw1, acc[1][1], 0, 0, 0);
        acc[1][2] = __builtin_amdgcn_mfma_f32_16x16x32_bf16(af1, bw2, acc[1][2], 0, 0, 0);
        acc[2][0] = __builtin_amdgcn_mfma_f32_16x16x32_bf16(af2, bw0, acc[2][0], 0, 0, 0);
        acc[2][1] = __builtin_amdgcn_mfma_f32_16x16x32_bf16(af2, bw1, acc[2][1], 0, 0, 0);
        acc[2][2] = __builtin_amdgcn_mfma_f32_16x16x32_bf16(af2, bw2, acc[2][2], 0, 0, 0);
        acc[3][0] = __builtin_amdgcn_mfma_f32_16x16x32_bf16(af3, bw0, acc[3][0], 0, 0, 0);
        acc[3][1] = __builtin_amdgcn_mfma_f32_16x16x32_bf16(af3, bw1, acc[3][1], 0, 0, 0);
        acc[3][2] = __builtin_amdgcn_mfma_f32_16x16x32_bf16(af3, bw2, acc[3][2], 0, 0, 0);
    }

    // ---- epilogue A: +b1, gelu -> Hs (local cols 0..192, stride 200) ----
#pragma unroll
    for (int i = 0; i < 3; ++i) {
        const int lc = w * 48 + i * 16 + lm;
        const float b1v = b1[half * 192 + lc];
#pragma unroll
        for (int mt = 0; mt < 4; ++mt)
#pragma unroll
            for (int r = 0; r < 4; ++r) {
                float h = gelu_fast(acc[mt][i][r] + b1v);
                Hs[(mt * 16 + q * 4 + r) * 200 + lc] = f2bf(h);
            }
    }
    __syncthreads();

    // ---- epilogue B: partial em = h_half @ W2_half via 6 MFMA ----
    f32x4 e = (f32x4)0.f;
#pragma unroll
    for (int kk = 0; kk < 6; ++kk) {
        short8 ah = *(const short8*)&Hs[(w * 16 + lm) * 200 + kk * 32 + (q << 3)];
        short8 bw = *(const short8*)(W2F + ((size_t)((half * 6 + kk) * 64 + lane)) * 8);
        e = __builtin_amdgcn_mfma_f32_16x16x32_bf16(ah, bw, e, 0, 0, 0);
    }
    if (lm < 9) {
        float* emo = half ? em1 : em0;
        const float badd = half ? 0.f : b2[lm];
#pragma unroll
        for (int r = 0; r < 4; ++r)
            emo[(size_t)(row0 + w * 16 + q * 4 + r) * T_ + lm] = e[r] + badd;
    }
}

// -----------------------------------------------------------------------------
// Kernel 2: CRF. 64 blocks x 640 threads.
// Phase A: threads 0..575 = (chunk c in [0,64), row i0) build 9x9 transfer
// matrices over 8 steps, trans in registers. Wave 9 (576..639) concurrently
// computes the numerator. Phase B: 6-level TREE combine of the 64 matrices
// (log-semiring matmul is associative). Final: alpha0 x M_total, logsumexp,
// atomicAdd of (denom-numer)/B into d_out (zeroed by prep).
// -----------------------------------------------------------------------------
__global__ __launch_bounds__(640) void crf_kernel(
    const float* __restrict__ em0,
    const float* __restrict__ em1,
    const int* __restrict__ labels,
    const unsigned char* __restrict__ maskb,
    const float* __restrict__ st,
    const float* __restrict__ et,
    const float* __restrict__ tr,
    float* __restrict__ out)
{
    const int b = blockIdx.x;
    const int t = threadIdx.x;

    __shared__ float es[64 * 73];    // es[c*73 + s*9 + j]
    __shared__ float Msa[64 * 81];
    __shared__ float Msb[32 * 81];
    __shared__ float trs[81];
    __shared__ float red_num;
    __shared__ unsigned char msh[L_];
    __shared__ int lbs[L_];

    const int mstride =
        (maskb[0] != 0 && maskb[1] == 0 && maskb[2] == 0 && maskb[3] == 0) ? 4 : 1;

    const float* e0 = em0 + (size_t)b * L_ * T_;
    const float* e1 = em1 + (size_t)b * L_ * T_;
    for (int i = t; i < L_ * T_; i += 640) {
        int tt = i / T_, j = i - tt * T_;
        es[(tt >> 3) * 73 + (tt & 7) * 9 + j] = e0[i] + e1[i];
    }
    if (t < 81) trs[t] = tr[t];
    for (int i = t; i < L_; i += 640) {
        msh[i] = maskb[((size_t)b * L_ + i) * (size_t)mstride];
        lbs[i] = labels[b * L_ + i];
    }
    __syncthreads();

    if (t < 576) {
        // ---- Phase A ----
        const int c  = t / 9;
        const int i0 = t - c * 9;
        float trr[81];
#pragma unroll
        for (int i = 0; i < 81; ++i) trr[i] = trs[i];
        float V[9];
#pragma unroll
        for (int j = 0; j < 9; ++j) V[j] = (j == i0) ? 0.f : -1e30f;

        const int sbeg = (c == 0) ? 1 : 0;
        for (int s = sbeg; s < 8; ++s) {
            int tt = c * 8 + s;
            if (msh[tt]) {
                const float* ep = &es[c * 73 + s * 9];
                float nv[9];
#pragma unroll
                for (int j = 0; j < 9; ++j) {
                    float a[9];
#pragma unroll
                    for (int k = 0; k < 9; ++k) a[k] = V[k] + trr[k * 9 + j];
                    float mx = a[0];
#pragma unroll
                    for (int k = 1; k < 9; ++k) mx = fmaxf(mx, a[k]);
                    float sum = 0.f;
#pragma unroll
                    for (int k = 0; k < 9; ++k) sum += __expf(a[k] - mx);
                    nv[j] = ep[j] + mx + __logf(sum);
                }
#pragma unroll
                for (int j = 0; j < 9; ++j) V[j] = nv[j];
            }
        }
#pragma unroll
        for (int j = 0; j < 9; ++j) Msa[c * 81 + i0 * 9 + j] = V[j];
    } else {
        // ---- numerator (wave 9, concurrent with Phase A) ----
        const int lane = t - 576;
        float emit_s = 0.f, tr_sc = 0.f, mcnt = 0.f;
        for (int tt = lane; tt < L_; tt += 64) {
            if (msh[tt]) {
                mcnt += 1.f;
                int tag = lbs[tt];
                emit_s += es[(tt >> 3) * 73 + (tt & 7) * 9 + tag];
                if (tt >= 1) tr_sc += trs[lbs[tt - 1] * 9 + tag];
            }
        }
        emit_s = wredf(emit_s);
        tr_sc  = wredf(tr_sc);
        mcnt   = wredf(mcnt);
        if (lane == 0) {
            int last = (int)mcnt - 1;
            red_num = st[lbs[0]] + emit_s + tr_sc + et[lbs[last]];
        }
    }
    __syncthreads();

    // ---- Phase B: tree combine, 6 levels ----
    float* src = Msa;
    float* dst = Msb;
    for (int n = 32; n >= 1; n >>= 1) {
        for (int idx = t; idx < n * 81; idx += 640) {
            int p = idx / 81;
            int r = idx - p * 81;
            int i = r / 9, j = r - i * 9;
            const float* A  = src + (2 * p) * 81 + i * 9;
            const float* Bm = src + (2 * p + 1) * 81 + j;
            float v[9];
#pragma unroll
            for (int k = 0; k < 9; ++k) v[k] = A[k] + Bm[k * 9];
            float mx = v[0];
#pragma unroll
            for (int k = 1; k < 9; ++k) mx = fmaxf(mx, v[k]);
            float sum = 0.f;
#pragma unroll
            for (int k = 0; k < 9; ++k) sum += __expf(v[k] - mx);
            dst[p * 81 + r] = mx + __logf(sum);
        }
        __syncthreads();
        float* tmp = src; src = dst; dst = tmp;
    }
    // final matrix in src (= Msa after 6 swaps)

    if (t < 64) {
        float v = -3.0e38f;
        if (t < 9) {
            float a[9];
#pragma unroll
            for (int i = 0; i < 9; ++i) a[i] = st[i] + es[i] + src[i * 9 + t];
            float mx = a[0];
#pragma unroll
            for (int i = 1; i < 9; ++i) mx = fmaxf(mx, a[i]);
            float sum = 0.f;
#pragma unroll
            for (int i = 0; i < 9; ++i) sum += __expf(a[i] - mx);
            v = mx + __logf(sum) + et[t];
        }
        float mx = v;
#pragma unroll
        for (int m = 32; m >= 1; m >>= 1) mx = fmaxf(mx, __shfl_xor(mx, m, 64));
        float sm = __expf(v - mx);
        sm = wredf(sm);
        if (t == 0) {
            float denom = mx + __logf(sm);
            atomicAdd(out, (denom - red_num) * (1.0f / (float)B_));
        }
    }
}

extern "C" void kernel_launch(void* const* d_in, const int* in_sizes, int n_in,
                              void* d_out, int out_size, void* d_ws, size_t ws_size,
                              hipStream_t stream) {
    const float*         enc    = (const float*)d_in[0];
    const int*           labels = (const int*)d_in[1];
    const unsigned char* mask   = (const unsigned char*)d_in[2];
    const float*         W1     = (const float*)d_in[3];
    const float*         b1     = (const float*)d_in[4];
    const float*         W2     = (const float*)d_in[5];
    const float*         b2     = (const float*)d_in[6];
    const float*         st     = (const float*)d_in[7];
    const float*         et     = (const float*)d_in[8];
    const float*         tr     = (const float*)d_in[9];

    float* em0          = (float*)d_ws;                        // 1,179,648 B
    float* em1          = em0 + (size_t)M_ * T_;               // 1,179,648 B
    unsigned short* W1F = (unsigned short*)(em1 + (size_t)M_ * T_);  // 589,824 B
    unsigned short* W2F = W1F + (size_t)576 * 64 * 8;          // 12,288 B

    prep_kernel<<<147, 256, 0, stream>>>(W1, W2, W1F, W2F, (float*)d_out);
    emis_mfma_kernel<<<1024, 256, 0, stream>>>(enc, W1F, b1, W2F, b2, em0, em1);
    crf_kernel<<<B_, 640, 0, stream>>>(em0, em1, labels, mask, st, et, tr, (float*)d_out);
}

// Round 5
// 220.520 us; speedup vs baseline: 1.3246x; 1.3246x over previous
//
#include <hip/hip_runtime.h>
#include <hip/hip_bf16.h>
#include <math.h>

#define B_ 64
#define L_ 512
#define D_ 768
#define H_ 384
#define T_ 9
#define M_ (B_ * L_)   // 32768 rows

typedef __attribute__((ext_vector_type(8))) short short8;
typedef __attribute__((ext_vector_type(4))) float f32x4;

__device__ __forceinline__ unsigned short f2bf(float f) {
    unsigned u = __float_as_uint(f);
    u += 0x7FFFu + ((u >> 16) & 1u);   // RNE
    return (unsigned short)(u >> 16);
}

// packed f32x2 -> bf16x2 (v_cvt_pk_bf16_f32 on gfx950)
__device__ __forceinline__ unsigned pkbf2(float a, float b) {
    __hip_bfloat162 h = __float22bfloat162_rn(float2{a, b});
    return *(unsigned*)&h;
}

// tanh-form gelu as x * sigmoid(2*0.79788456*(x + 0.044715 x^3)) — 1 exp.
__device__ __forceinline__ float gelu_fast(float x) {
    float z2 = 1.5957691216f * x + 0.0713548162726f * x * x * x;
    return x / (1.f + __expf(-z2));
}

__device__ __forceinline__ float wredf(float v) {
#pragma unroll
    for (int m = 32; m >= 1; m >>= 1) v += __shfl_xor(v, m, 64);
    return v;
}

// LDS-only barrier: global loads stay in flight across it (no vmcnt drain).
__device__ __forceinline__ void sync_lds() {
    asm volatile("s_waitcnt lgkmcnt(0)\n\ts_barrier" ::: "memory");
}

// -----------------------------------------------------------------------------
// Kernel 0: fragment-ordered bf16 weights + zero d_out.
//   W1F[((nt*24 + kc)*64 + lane)*8 + j] = W1[kc*32 + q*8 + j][nt*16 + lm]
//   W2F[(kk*64 + lane)*8 + j]           = (lm<9) ? W2[kk*32 + q*8 + j][lm] : 0
// -----------------------------------------------------------------------------
__global__ __launch_bounds__(256) void prep_kernel(
    const float* __restrict__ W1, const float* __restrict__ W2,
    unsigned short* __restrict__ W1F, unsigned short* __restrict__ W2F,
    float* __restrict__ out)
{
    if (blockIdx.x == 0 && threadIdx.x == 0) out[0] = 0.f;
    const int g    = blockIdx.x * 4 + (threadIdx.x >> 6);
    const int lane = threadIdx.x & 63;
    const int lm   = lane & 15;
    const int q    = lane >> 4;
    if (g < 576) {                       // W1F: g = nt*24 + kc
        const int nt = g / 24;
        const int kc = g - nt * 24;
        const int n  = nt * 16 + lm;
        short8 v;
#pragma unroll
        for (int j = 0; j < 8; ++j)
            v[j] = (short)f2bf(W1[(size_t)(kc * 32 + q * 8 + j) * H_ + n]);
        *(short8*)(W1F + ((size_t)g * 64 + lane) * 8) = v;
    } else if (g < 588) {                // W2F: kk = g - 576
        const int kk = g - 576;
        short8 v;
#pragma unroll
        for (int j = 0; j < 8; ++j) {
            int k = kk * 32 + q * 8 + j;
            v[j] = (lm < 9) ? (short)f2bf(W2[(size_t)k * T_ + lm]) : (short)0;
        }
        *(short8*)(W2F + ((size_t)kk * 64 + lane) * 8) = v;
    }
}

// -----------------------------------------------------------------------------
// Kernel 1: emissions. Grid 512 row-blocks (= exactly 2 blocks/CU resident,
// no tail). BM=64, FULL N=384, 256 thr: wave w owns n-tiles w*6..w*6+5
// (4 m-tiles x 6 n-tiles = 24 MFMA/iter, acc[4][6]).
//
// A-tile staged as BF16 in LDS (reg-staged T14): 256 threads load tile fp32 ->
// regs (3-deep prefetch), cvt_pk -> bf16x8, one ds_write_b128 each into a
// 4 KB buffer (x2, double-buffered). Swizzle addr = row*64 +
// (chunk ^ ((row>>1)&3))*16 gives exactly 8 words/bank on BOTH ds_write_b128
// and ds_read_b128 (the b128 floor — r3's swizzle was a no-op: fp32 row
// stride 128 B == 32 banks). Read path: 1 ds_read_b128 per m-tile, NO cvt.
//
// Sync: ONE lgkm-only barrier per k-step (publishes ds_writes). Global loads
// (A kc+3, W1F frags kc+1) are register-consumed -> compiler emits counted
// vmcnt waits; nothing ever drains vmcnt at a barrier (r1/r2 lesson).
// All register buffers are token-pasted named sets with literal indices
// (rule #20; r2 scratch-spill lesson).
// Epilogue: gelu -> Hs[64][392] bf16 (aliases A-bufs after syncthreads) ->
// 12 MFMA vs full W2F -> em (+b2), single buffer.
// -----------------------------------------------------------------------------
__global__ __launch_bounds__(256, 2) void emis_mfma_kernel(
    const float* __restrict__ X,             // [M_][768] fp32
    const unsigned short* __restrict__ W1F,
    const float* __restrict__ b1,
    const unsigned short* __restrict__ W2F,
    const float* __restrict__ b2,
    float* __restrict__ em)                  // [M_][9] full emissions (+b2)
{
    __shared__ __align__(16) unsigned short Hs[64 * 392];  // 50176 B
    char* smem = (char*)Hs;                  // As[2][4096 B] aliases the head

    const int t    = threadIdx.x;
    const int lane = t & 63;
    const int w    = t >> 6;
    const int lm   = lane & 15;
    const int q    = lane >> 4;
    const int row0 = blockIdx.x * 64;

    // staging: thread t handles row srow = t>>2, col-chunk scb = t&3
    // (8 fp32 = 32 B global -> 16 B bf16), swizzled LDS slot.
    const int srow  = t >> 2;
    const int scb   = t & 3;
    const int sslot = scb ^ ((srow >> 1) & 3);
    const float* sp = X + (size_t)(row0 + srow) * D_ + scb * 8;
    char* swr = smem + srow * 64 + sslot * 16;       // + buf*4096

    // fragment read: row mt*16+lm, swizzled chunk q  [(row>>1)&3 == (lm>>1)&3]
    const int cq = (q ^ ((lm >> 1) & 3)) << 4;       // byte offset

    // W1F base for this wave (offsets in shorts: nt*12288 + kc*512 + lane*8)
    const unsigned short* wb = W1F + (size_t)(w * 6) * 12288 + lane * 8;

    f32x4 acc[4][6];
#pragma unroll
    for (int mt = 0; mt < 4; ++mt)
#pragma unroll
        for (int i = 0; i < 6; ++i) acc[mt][i] = (f32x4)0.f;

    short8 bbA[6], bbB[6];                   // alternating B-frag sets
    f32x4 gA0, gA1, gB0, gB1, gC0, gC1;      // rotating A-stage sets (tile%3)

#define LOADBB(dst, KC)                                                     \
    do {                                                                    \
        dst[0] = *(const short8*)(wb + 0 * 12288 + (KC) * 512);             \
        dst[1] = *(const short8*)(wb + 1 * 12288 + (KC) * 512);             \
        dst[2] = *(const short8*)(wb + 2 * 12288 + (KC) * 512);             \
        dst[3] = *(const short8*)(wb + 3 * 12288 + (KC) * 512);             \
        dst[4] = *(const short8*)(wb + 4 * 12288 + (KC) * 512);             \
        dst[5] = *(const short8*)(wb + 5 * 12288 + (KC) * 512);             \
    } while (0)

    // ---- prologue: tiles 0,1,2 -> gA,gB,gC; frags(0); write tile0 -> buf0
    gA0 = *(const f32x4*)(sp);       gA1 = *(const f32x4*)(sp + 4);
    gB0 = *(const f32x4*)(sp + 32);  gB1 = *(const f32x4*)(sp + 36);
    gC0 = *(const f32x4*)(sp + 64);  gC1 = *(const f32x4*)(sp + 68);
    LOADBB(bbA, 0);
    {
        int4 v = {(int)pkbf2(gA0[0], gA0[1]), (int)pkbf2(gA0[2], gA0[3]),
                  (int)pkbf2(gA1[0], gA1[1]), (int)pkbf2(gA1[2], gA1[3])};
        *(int4*)(swr) = v;
    }
    sync_lds();

    // KSTEP(KC): consume G(KC+1) -> buf[(KC+1)&1]; issue G(KC+3), BB(KC+1);
    // MFMA tile KC from buf[KC&1] with BBc. One lgkm barrier at the end.
#define KSTEP(KC, BBc, BBn, Gc0, Gc1, Gn0, Gn1)                             \
    do {                                                                    \
        if ((KC) + 3 <= 23) {                                               \
            Gn0 = *(const f32x4*)(sp + ((KC) + 3) * 32);                    \
            Gn1 = *(const f32x4*)(sp + ((KC) + 3) * 32 + 4);                \
        }                                                                   \
        if ((KC) + 1 <= 23) { LOADBB(BBn, (KC) + 1); }                      \
        {                                                                   \
            const char* fb = smem + ((KC) & 1) * 4096;                      \
            short8 af0 = *(const short8*)(fb + (0 * 16 + lm) * 64 + cq);    \
            short8 af1 = *(const short8*)(fb + (1 * 16 + lm) * 64 + cq);    \
            short8 af2 = *(const short8*)(fb + (2 * 16 + lm) * 64 + cq);    \
            short8 af3 = *(const short8*)(fb + (3 * 16 + lm) * 64 + cq);    \
            acc[0][0] = __builtin_amdgcn_mfma_f32_16x16x32_bf16(af0, BBc[0], acc[0][0], 0, 0, 0); \
            acc[0][1] = __builtin_amdgcn_mfma_f32_16x16x32_bf16(af0, BBc[1], acc[0][1], 0, 0, 0); \
            acc[0][2] = __builtin_amdgcn_mfma_f32_16x16x32_bf16(af0, BBc[2], acc[0][2], 0, 0, 0); \
            acc[0][3] = __builtin_amdgcn_mfma_f32_16x16x32_bf16(af0, BBc[3], acc[0][3], 0, 0, 0); \
            acc[0][4] = __builtin_amdgcn_mfma_f32_16x16x32_bf16(af0, BBc[4], acc[0][4], 0, 0, 0); \
            acc[0][5] = __builtin_amdgcn_mfma_f32_16x16x32_bf16(af0, BBc[5], acc[0][5], 0, 0, 0); \
            acc[1][0] = __builtin_amdgcn_mfma_f32_16x16x32_bf16(af1, BBc[0], acc[1][0], 0, 0, 0); \
            acc[1][1] = __builtin_amdgcn_mfma_f32_16x16x32_bf16(af1, BBc[1], acc[1][1], 0, 0, 0); \
            acc[1][2] = __builtin_amdgcn_mfma_f32_16x16x32_bf16(af1, BBc[2], acc[1][2], 0, 0, 0); \
            acc[1][3] = __builtin_amdgcn_mfma_f32_16x16x32_bf16(af1, BBc[3], acc[1][3], 0, 0, 0); \
            acc[1][4] = __builtin_amdgcn_mfma_f32_16x16x32_bf16(af1, BBc[4], acc[1][4], 0, 0, 0); \
            acc[1][5] = __builtin_amdgcn_mfma_f32_16x16x32_bf16(af1, BBc[5], acc[1][5], 0, 0, 0); \
            acc[2][0] = __builtin_amdgcn_mfma_f32_16x16x32_bf16(af2, BBc[0], acc[2][0], 0, 0, 0); \
            acc[2][1] = __builtin_amdgcn_mfma_f32_16x16x32_bf16(af2, BBc[1], acc[2][1], 0, 0, 0); \
            acc[2][2] = __builtin_amdgcn_mfma_f32_16x16x32_bf16(af2, BBc[2], acc[2][2], 0, 0, 0); \
            acc[2][3] = __builtin_amdgcn_mfma_f32_16x16x32_bf16(af2, BBc[3], acc[2][3], 0, 0, 0); \
            acc[2][4] = __builtin_amdgcn_mfma_f32_16x16x32_bf16(af2, BBc[4], acc[2][4], 0, 0, 0); \
            acc[2][5] = __builtin_amdgcn_mfma_f32_16x16x32_bf16(af2, BBc[5], acc[2][5], 0, 0, 0); \
            acc[3][0] = __builtin_amdgcn_mfma_f32_16x16x32_bf16(af3, BBc[0], acc[3][0], 0, 0, 0); \
            acc[3][1] = __builtin_amdgcn_mfma_f32_16x16x32_bf16(af3, BBc[1], acc[3][1], 0, 0, 0); \
            acc[3][2] = __builtin_amdgcn_mfma_f32_16x16x32_bf16(af3, BBc[2], acc[3][2], 0, 0, 0); \
            acc[3][3] = __builtin_amdgcn_mfma_f32_16x16x32_bf16(af3, BBc[3], acc[3][3], 0, 0, 0); \
            acc[3][4] = __builtin_amdgcn_mfma_f32_16x16x32_bf16(af3, BBc[4], acc[3][4], 0, 0, 0); \
            acc[3][5] = __builtin_amdgcn_mfma_f32_16x16x32_bf16(af3, BBc[5], acc[3][5], 0, 0, 0); \
        }                                                                   \
        if ((KC) + 1 <= 23) {                                               \
            int4 v = {(int)pkbf2(Gc0[0], Gc0[1]), (int)pkbf2(Gc0[2], Gc0[3]), \
                      (int)pkbf2(Gc1[0], Gc1[1]), (int)pkbf2(Gc1[2], Gc1[3])}; \
            *(int4*)(swr + (((KC) + 1) & 1) * 4096) = v;                    \
            sync_lds();                                                     \
        }                                                                   \
    } while (0)

    KSTEP(0,  bbA, bbB, gB0, gB1, gA0, gA1);
    KSTEP(1,  bbB, bbA, gC0, gC1, gB0, gB1);
    KSTEP(2,  bbA, bbB, gA0, gA1, gC0, gC1);
    KSTEP(3,  bbB, bbA, gB0, gB1, gA0, gA1);
    KSTEP(4,  bbA, bbB, gC0, gC1, gB0, gB1);
    KSTEP(5,  bbB, bbA, gA0, gA1, gC0, gC1);
    KSTEP(6,  bbA, bbB, gB0, gB1, gA0, gA1);
    KSTEP(7,  bbB, bbA, gC0, gC1, gB0, gB1);
    KSTEP(8,  bbA, bbB, gA0, gA1, gC0, gC1);
    KSTEP(9,  bbB, bbA, gB0, gB1, gA0, gA1);
    KSTEP(10, bbA, bbB, gC0, gC1, gB0, gB1);
    KSTEP(11, bbB, bbA, gA0, gA1, gC0, gC1);
    KSTEP(12, bbA, bbB, gB0, gB1, gA0, gA1);
    KSTEP(13, bbB, bbA, gC0, gC1, gB0, gB1);
    KSTEP(14, bbA, bbB, gA0, gA1, gC0, gC1);
    KSTEP(15, bbB, bbA, gB0, gB1, gA0, gA1);
    KSTEP(16, bbA, bbB, gC0, gC1, gB0, gB1);
    KSTEP(17, bbB, bbA, gA0, gA1, gC0, gC1);
    KSTEP(18, bbA, bbB, gB0, gB1, gA0, gA1);
    KSTEP(19, bbB, bbA, gC0, gC1, gB0, gB1);
    KSTEP(20, bbA, bbB, gA0, gA1, gC0, gC1);
    KSTEP(21, bbB, bbA, gB0, gB1, gA0, gA1);
    KSTEP(22, bbA, bbB, gC0, gC1, gB0, gB1);
    KSTEP(23, bbB, bbA, gA0, gA1, gC0, gC1);

#undef KSTEP
#undef LOADBB

    __syncthreads();   // all ds_reads done before Hs (alias) is written

    // ---- epilogue A: +b1, gelu -> Hs[64][392] (full 384 cols) ----
#pragma unroll
    for (int i = 0; i < 6; ++i) {
        const int lc = w * 96 + i * 16 + lm;
        const float b1v = b1[lc];
#pragma unroll
        for (int mt = 0; mt < 4; ++mt)
#pragma unroll
            for (int r = 0; r < 4; ++r) {
                float h = gelu_fast(acc[mt][i][r] + b1v);
                Hs[(mt * 16 + q * 4 + r) * 392 + lc] = f2bf(h);
            }
    }
    __syncthreads();

    // ---- epilogue B: em = h @ W2 via 12 MFMA, +b2, single buffer ----
    f32x4 e = (f32x4)0.f;
#pragma unroll
    for (int kk = 0; kk < 12; ++kk) {
        short8 ah = *(const short8*)&Hs[(w * 16 + lm) * 392 + kk * 32 + (q << 3)];
        short8 bw = *(const short8*)(W2F + ((size_t)(kk * 64 + lane)) * 8);
        e = __builtin_amdgcn_mfma_f32_16x16x32_bf16(ah, bw, e, 0, 0, 0);
    }
    if (lm < 9) {
#pragma unroll
        for (int r = 0; r < 4; ++r)
            em[(size_t)(row0 + w * 16 + q * 4 + r) * T_ + lm] = e[r] + b2[lm];
    }
}

// -----------------------------------------------------------------------------
// Kernel 2: CRF. 64 blocks x 640 threads. (Single em input now.)
// Phase A: threads 0..575 = (chunk c, row i0) build 9x9 transfer matrices;
// wave 9 computes the numerator concurrently. Phase B: 6-level tree combine.
// Final: alpha0 x M_total, logsumexp, atomicAdd (denom-numer)/B.
// -----------------------------------------------------------------------------
__global__ __launch_bounds__(640) void crf_kernel(
    const float* __restrict__ em,
    const int* __restrict__ labels,
    const unsigned char* __restrict__ maskb,
    const float* __restrict__ st,
    const float* __restrict__ et,
    const float* __restrict__ tr,
    float* __restrict__ out)
{
    const int b = blockIdx.x;
    const int t = threadIdx.x;

    __shared__ float es[64 * 73];    // es[c*73 + s*9 + j]
    __shared__ float Msa[64 * 81];
    __shared__ float Msb[32 * 81];
    __shared__ float trs[81];
    __shared__ float red_num;
    __shared__ unsigned char msh[L_];
    __shared__ int lbs[L_];

    const int mstride =
        (maskb[0] != 0 && maskb[1] == 0 && maskb[2] == 0 && maskb[3] == 0) ? 4 : 1;

    const float* e0 = em + (size_t)b * L_ * T_;
    for (int i = t; i < L_ * T_; i += 640) {
        int tt = i / T_, j = i - tt * T_;
        es[(tt >> 3) * 73 + (tt & 7) * 9 + j] = e0[i];
    }
    if (t < 81) trs[t] = tr[t];
    for (int i = t; i < L_; i += 640) {
        msh[i] = maskb[((size_t)b * L_ + i) * (size_t)mstride];
        lbs[i] = labels[b * L_ + i];
    }
    __syncthreads();

    if (t < 576) {
        // ---- Phase A ----
        const int c  = t / 9;
        const int i0 = t - c * 9;
        float trr[81];
#pragma unroll
        for (int i = 0; i < 81; ++i) trr[i] = trs[i];
        float V[9];
#pragma unroll
        for (int j = 0; j < 9; ++j) V[j] = (j == i0) ? 0.f : -1e30f;

        const int sbeg = (c == 0) ? 1 : 0;
        for (int s = sbeg; s < 8; ++s) {
            int tt = c * 8 + s;
            if (msh[tt]) {
                const float* ep = &es[c * 73 + s * 9];
                float nv[9];
#pragma unroll
                for (int j = 0; j < 9; ++j) {
                    float a[9];
#pragma unroll
                    for (int k = 0; k < 9; ++k) a[k] = V[k] + trr[k * 9 + j];
                    float mx = a[0];
#pragma unroll
                    for (int k = 1; k < 9; ++k) mx = fmaxf(mx, a[k]);
                    float sum = 0.f;
#pragma unroll
                    for (int k = 0; k < 9; ++k) sum += __expf(a[k] - mx);
                    nv[j] = ep[j] + mx + __logf(sum);
                }
#pragma unroll
                for (int j = 0; j < 9; ++j) V[j] = nv[j];
            }
        }
#pragma unroll
        for (int j = 0; j < 9; ++j) Msa[c * 81 + i0 * 9 + j] = V[j];
    } else {
        // ---- numerator (wave 9, concurrent with Phase A) ----
        const int lane = t - 576;
        float emit_s = 0.f, tr_sc = 0.f, mcnt = 0.f;
        for (int tt = lane; tt < L_; tt += 64) {
            if (msh[tt]) {
                mcnt += 1.f;
                int tag = lbs[tt];
                emit_s += es[(tt >> 3) * 73 + (tt & 7) * 9 + tag];
                if (tt >= 1) tr_sc += trs[lbs[tt - 1] * 9 + tag];
            }
        }
        emit_s = wredf(emit_s);
        tr_sc  = wredf(tr_sc);
        mcnt   = wredf(mcnt);
        if (lane == 0) {
            int last = (int)mcnt - 1;
            red_num = st[lbs[0]] + emit_s + tr_sc + et[lbs[last]];
        }
    }
    __syncthreads();

    // ---- Phase B: tree combine, 6 levels ----
    float* src = Msa;
    float* dst = Msb;
    for (int n = 32; n >= 1; n >>= 1) {
        for (int idx = t; idx < n * 81; idx += 640) {
            int p = idx / 81;
            int r = idx - p * 81;
            int i = r / 9, j = r - i * 9;
            const float* A  = src + (2 * p) * 81 + i * 9;
            const float* Bm = src + (2 * p + 1) * 81 + j;
            float v[9];
#pragma unroll
            for (int k = 0; k < 9; ++k) v[k] = A[k] + Bm[k * 9];
            float mx = v[0];
#pragma unroll
            for (int k = 1; k < 9; ++k) mx = fmaxf(mx, v[k]);
            float sum = 0.f;
#pragma unroll
            for (int k = 0; k < 9; ++k) sum += __expf(v[k] - mx);
            dst[p * 81 + r] = mx + __logf(sum);
        }
        __syncthreads();
        float* tmp = src; src = dst; dst = tmp;
    }
    // final matrix in src (= Msa after 6 swaps)

    if (t < 64) {
        float v = -3.0e38f;
        if (t < 9) {
            float a[9];
#pragma unroll
            for (int i = 0; i < 9; ++i) a[i] = st[i] + es[i] + src[i * 9 + t];
            float mx = a[0];
#pragma unroll
            for (int i = 1; i < 9; ++i) mx = fmaxf(mx, a[i]);
            float sum = 0.f;
#pragma unroll
            for (int i = 0; i < 9; ++i) sum += __expf(a[i] - mx);
            v = mx + __logf(sum) + et[t];
        }
        float mx = v;
#pragma unroll
        for (int m = 32; m >= 1; m >>= 1) mx = fmaxf(mx, __shfl_xor(mx, m, 64));
        float sm = __expf(v - mx);
        sm = wredf(sm);
        if (t == 0) {
            float denom = mx + __logf(sm);
            atomicAdd(out, (denom - red_num) * (1.0f / (float)B_));
        }
    }
}

extern "C" void kernel_launch(void* const* d_in, const int* in_sizes, int n_in,
                              void* d_out, int out_size, void* d_ws, size_t ws_size,
                              hipStream_t stream) {
    const float*         enc    = (const float*)d_in[0];
    const int*           labels = (const int*)d_in[1];
    const unsigned char* mask   = (const unsigned char*)d_in[2];
    const float*         W1     = (const float*)d_in[3];
    const float*         b1     = (const float*)d_in[4];
    const float*         W2     = (const float*)d_in[5];
    const float*         b2     = (const float*)d_in[6];
    const float*         st     = (const float*)d_in[7];
    const float*         et     = (const float*)d_in[8];
    const float*         tr     = (const float*)d_in[9];

    float* em           = (float*)d_ws;                        // 1,179,648 B
    unsigned short* W1F = (unsigned short*)(em + (size_t)M_ * T_);   // 589,824 B
    unsigned short* W2F = W1F + (size_t)576 * 64 * 8;          // 12,288 B

    prep_kernel<<<147, 256, 0, stream>>>(W1, W2, W1F, W2F, (float*)d_out);
    emis_mfma_kernel<<<512, 256, 0, stream>>>(enc, W1F, b1, W2F, b2, em);
    crf_kernel<<<B_, 640, 0, stream>>>(em, labels, mask, st, et, tr, (float*)d_out);
}